// Round 15
// baseline (56.499 us; speedup 1.0000x reference)
//
#include <hip/hip_runtime.h>

// EdgeSelectionRL: out[b,i,j] = sigmoid( sum_h relu(A[b,i,h] + Cc[b,j,h]) * w2[h] + b2 )
// A = xa·Wa^T + b1, Cc = xa·Wb^T.  B=8, C=256, F=128, H=256.
// R15 = R12 (1-node LDS-staged fused, verified-correct) + rule#20 fix:
// Phase B g-loop FULLY unrolled so w2r[g] is static-indexed (R9-R12's
// "#pragma unroll 2" left g dynamic -> w2r/acc spilled to scratch ->
// VGPR=56, all pipes idle, 128-182us). + readfirstlane on hs/ih.
// Replay model: dur ~= max(~15us submission floor + 2us/extra node, device).

typedef _Float16 h2 __attribute__((ext_vector_type(2)));
typedef _Float16 h4 __attribute__((ext_vector_type(4)));
typedef _Float16 h8 __attribute__((ext_vector_type(8)));
typedef float    f4 __attribute__((ext_vector_type(4)));

constexpr int B  = 8;
constexpr int C  = 256;
constexpr int F  = 128;
constexpr int H  = 256;
constexpr int F2 = 2 * F;     // 256
constexpr int AP = H + 8;     // 264: padded A_s pitch

#if __has_builtin(__builtin_amdgcn_fdot2)
__device__ __forceinline__ float fdot2(h2 a, h2 b, float c) {
    return __builtin_amdgcn_fdot2(a, b, c, false);
}
#else
__device__ __forceinline__ float fdot2(h2 a, h2 b, float c) {
    return c + (float)a.x * (float)b.x + (float)a.y * (float)b.y;
}
#endif

union HU { h8 v; h2 p[4]; };

__device__ __forceinline__ h2 pkrtz(float x, float y) {
    return __builtin_bit_cast(h2, __builtin_amdgcn_cvt_pkrtz(x, y));
}

__device__ __forceinline__ h8 cvt8(float4 a, float4 b) {
    HU u;
    u.p[0] = pkrtz(a.x, a.y);
    u.p[1] = pkrtz(a.z, a.w);
    u.p[2] = pkrtz(b.x, b.y);
    u.p[3] = pkrtz(b.z, b.w);
    return u.v;
}

__device__ __forceinline__ float4 ldg4(const float* p) {
    return *(const float4*)p;
}

// Grid 256 = b(8) x it(8) x jt(4). 1024 threads = 16 waves.
// Phase A: 96 tiles (A: 2x16ht=32, Cc: 4x16ht=64), 6 per wave. SWAPPED mfma:
//   D row=(l>>4)*4+r -> h (4 consecutive), col=l&15 -> x-row. One b64 LDS write.
// Phase B: wave wv: hs=wv&3 (64-h slice), ih=wv>>2 (8 i-rows); lane l = j.
__global__ __launch_bounds__(1024) void fused(
    const float* __restrict__ xa, const float* __restrict__ W1,
    const float* __restrict__ b1, const float* __restrict__ w2,
    const float* __restrict__ b2p, float* __restrict__ out)
{
    __shared__ _Float16 As[32 * AP];      // 16.5 KB  [i][h] padded
    __shared__ h8       Cs[32 * 64];      // 32 KB    [oct][j] octet-packed
    __shared__ float    red[3 * 32 * 64]; // 24 KB
    const int t   = threadIdx.x;
    const int blk = blockIdx.x;
    const int b   = blk >> 5;
    const int it  = (blk >> 2) & 7;
    const int jt  = blk & 3;
    const int i0  = it * 32;
    const int j0  = jt * 64;
    const int wv  = t >> 6;              // 0..15
    const int l   = t & 63;
    const int lm  = l & 15;
    const int lk  = (l >> 4) * 8;
    const int lq  = (l >> 4) * 4;        // h-quad offset in D
    const int hs  = __builtin_amdgcn_readfirstlane(wv & 3);   // SGPR
    const int ih  = __builtin_amdgcn_readfirstlane(wv >> 2);  // SGPR

    // ---- w2 slice -> registers (independent; overlaps phase A) ----
    h8 w2r[8];
    #pragma unroll
    for (int o = 0; o < 8; ++o) {
        const float* wq = w2 + (hs * 8 + o) * 8;
        w2r[o] = cvt8(ldg4(wq), ldg4(wq + 4));
    }

    // ---------------- Phase A: projection tiles -> LDS ----------------
    #pragma unroll 2
    for (int T = wv * 6; T < wv * 6 + 6; ++T) {
        const bool ctype = T >= 32;          // wave-uniform per T
        const int Tt  = ctype ? T - 32 : T;
        const int mt  = Tt >> 4;             // A: 0..1, Cc: 0..3
        const int ht  = Tt & 15;
        const int m0G = b * C + (ctype ? j0 : i0) + mt * 16;  // global xa row base
        const int h0  = ht * 16;
        const float* xp = xa + (size_t)(m0G + lm) * F + lk;
        const float* wp = W1 + (size_t)(h0 + lm) * F2 + lk + (ctype ? F : 0);

        f4 acc = {0.f, 0.f, 0.f, 0.f};
        #pragma unroll
        for (int kk = 0; kk < 4; ++kk) {
            h8 wf = cvt8(ldg4(wp + kk * 32), ldg4(wp + kk * 32 + 4));
            h8 af = cvt8(ldg4(xp + kk * 32), ldg4(xp + kk * 32 + 4));
            // SWAPPED operands: D[row=h-quad][col=x-row]
            acc = __builtin_amdgcn_mfma_f32_16x16x32_f16(wf, af, acc, 0, 0, 0);
        }

        const int hq = h0 + lq;              // 4 consecutive h for this lane
        const int mL = mt * 16 + lm;         // local row (i: 0..31, j: 0..63)
        if (!ctype) {
            const float4 bq = ldg4(b1 + hq);
            h2 v01 = pkrtz(acc[0] + bq.x, acc[1] + bq.y);
            h2 v23 = pkrtz(acc[2] + bq.z, acc[3] + bq.w);
            h4 v; v[0] = v01[0]; v[1] = v01[1]; v[2] = v23[0]; v[3] = v23[1];
            *(h4*)(&As[mL * AP + hq]) = v;   // 8B write, 2-way banks (free)
        } else {
            h2 v01 = pkrtz(acc[0], acc[1]);
            h2 v23 = pkrtz(acc[2], acc[3]);
            h4 v; v[0] = v01[0]; v[1] = v01[1]; v[2] = v23[0]; v[3] = v23[1];
            // Cs[oct][j][h&7]: hq&7 is 0 or 4 -> 8B-aligned half of the h8
            *(h4*)((_Float16*)&Cs[(hq >> 3) * 64 + mL] + (hq & 7)) = v;
        }
    }

    __syncthreads();   // LDS writes visible block-wide

    // ---------------- Phase B: dot2 pairwise from LDS ----------------
    float acc[8];
    #pragma unroll
    for (int ii = 0; ii < 8; ++ii) acc[ii] = 0.f;

    const _Float16* Ab = &As[(ih * 8) * AP + hs * 64];   // wave-uniform rows
    const h8*       Cb = &Cs[(hs * 8) * 64 + l];         // 16B/lane contiguous
    const h8 z = {0, 0, 0, 0, 0, 0, 0, 0};

    #pragma unroll                       // FULL unroll: w2r[g] static (rule #20)
    for (int g = 0; g < 8; ++g) {
        h8 cc = Cb[g * 64];                               // ds_read_b128
        HU uw; uw.v = w2r[g];
        #pragma unroll
        for (int ii = 0; ii < 8; ++ii) {
            h8 ao = *(const h8*)(Ab + ii * AP + g * 8);   // broadcast read
            h8 s  = __builtin_elementwise_max(ao + cc, z);
            HU us; us.v = s;
            float a0 = acc[ii];
            a0 = fdot2(us.p[0], uw.p[0], a0);
            a0 = fdot2(us.p[1], uw.p[1], a0);
            a0 = fdot2(us.p[2], uw.p[2], a0);
            a0 = fdot2(us.p[3], uw.p[3], a0);
            acc[ii] = a0;
        }
    }

    if (hs > 0) {
        #pragma unroll
        for (int ii = 0; ii < 8; ++ii)
            red[((hs - 1) * 32 + ih * 8 + ii) * 64 + l] = acc[ii];
    }
    __syncthreads();
    if (hs == 0) {
        const float bb = b2p[0];
        #pragma unroll
        for (int ii = 0; ii < 8; ++ii) {
            const int row = ih * 8 + ii;
            float x = acc[ii]
                    + red[(0 * 32 + row) * 64 + l]
                    + red[(1 * 32 + row) * 64 + l]
                    + red[(2 * 32 + row) * 64 + l] + bb;
            out[(size_t)(b * C + i0 + row) * C + j0 + l] = 1.f / (1.f + __expf(-x));
        }
    }
}

extern "C" void kernel_launch(void* const* d_in, const int* in_sizes, int n_in,
                              void* d_out, int out_size, void* d_ws, size_t ws_size,
                              hipStream_t stream) {
    const float* xa = (const float*)d_in[0];
    const float* W1 = (const float*)d_in[1];
    const float* b1 = (const float*)d_in[2];
    const float* w2 = (const float*)d_in[3];
    const float* b2 = (const float*)d_in[4];
    float* out = (float*)d_out;

    fused<<<256, 1024, 0, stream>>>(xa, W1, b1, w2, b2, out);
}

// Round 16
// 21.461 us; speedup vs baseline: 2.6327x; 2.6327x over previous
//
#include <hip/hip_runtime.h>

// EdgeSelectionRL: out[b,i,j] = sigmoid( sum_h relu(A[b,i,h] + Cc[b,j,h]) * w2[h] + b2 )
// A = xa·Wa^T + b1, Cc = xa·Wb^T.  B=8, C=256, F=128, H=256.
// R16 = R14 (best, 20.49us) + k1 epilogue tightened: SWAPPED mfma(W,X) so each
// lane holds 4 consecutive h per row -> 4x 8B h4 stores (was 16x 2B scalar),
// b1 via one float4. k2 (readfirstlane-uniform dot2) verbatim R14.
// Ledger: fused 1-node dead (5 tries, 45-182us device, pipes idle);
// 2-node floor ~= submission (~16us) + 2 nodes + ~4us device work.

typedef _Float16 h2 __attribute__((ext_vector_type(2)));
typedef _Float16 h4 __attribute__((ext_vector_type(4)));
typedef _Float16 h8 __attribute__((ext_vector_type(8)));
typedef float    f4 __attribute__((ext_vector_type(4)));

constexpr int B  = 8;
constexpr int C  = 256;
constexpr int F  = 128;
constexpr int H  = 256;
constexpr int F2 = 2 * F;     // 256
constexpr int HOCT = H / 8;   // 32

#if __has_builtin(__builtin_amdgcn_fdot2)
__device__ __forceinline__ float fdot2(h2 a, h2 b, float c) {
    return __builtin_amdgcn_fdot2(a, b, c, false);
}
#else
__device__ __forceinline__ float fdot2(h2 a, h2 b, float c) {
    return c + (float)a.x * (float)b.x + (float)a.y * (float)b.y;
}
#endif

union HU { h8 v; h2 p[4]; };

__device__ __forceinline__ h2 pkrtz(float x, float y) {
    return __builtin_bit_cast(h2, __builtin_amdgcn_cvt_pkrtz(x, y));
}

__device__ __forceinline__ h8 cvt8(float4 a, float4 b) {
    HU u;
    u.p[0] = pkrtz(a.x, a.y);
    u.p[1] = pkrtz(a.z, a.w);
    u.p[2] = pkrtz(b.x, b.y);
    u.p[3] = pkrtz(b.z, b.w);
    return u.v;
}

__device__ __forceinline__ float4 ldg4(const float* p) {
    return *(const float4*)p;
}

// ---------------- Kernel 1: projections via SWAPPED MFMA ----------------
// 256 blocks x 256 thr = 1024 waves. Wave w: 2 m-tiles at (w>>4)*32,
// h-tile (w&15)*16. mfma(wf, xf): D lane l reg r = Out[m0+(l&15)][h0+(l>>4)*4+r]
// -> pack h4, ONE 8B store per (tile, operand). R13-verified store pattern.
__global__ __launch_bounds__(256) void k1_mfma(
    const float* __restrict__ xa, const float* __restrict__ W1,
    const float* __restrict__ b1, const float* __restrict__ w2,
    _Float16* __restrict__ Ah, _Float16* __restrict__ CP8,
    _Float16* __restrict__ w2h)
{
    const int t  = threadIdx.x;
    const int w  = blockIdx.x * 4 + (t >> 6);   // 0..1023
    const int l  = t & 63;
    const int mg = w >> 4;                      // 0..63
    const int h0 = (w & 15) * 16;
    const int lm = l & 15;
    const int lk = (l >> 4) * 8;
    const int lq = (l >> 4) * 4;
    const int m0 = mg * 32;

    // A-operand fragments for both m-tiles (rows m0+lm, m0+16+lm)
    h8 xf0[4], xf1[4];
    const float* xp0 = xa + (size_t)(m0 + lm) * F + lk;
    const float* xp1 = xp0 + 16 * F;
    #pragma unroll
    for (int kk = 0; kk < 4; ++kk) {
        xf0[kk] = cvt8(ldg4(xp0 + kk * 32), ldg4(xp0 + kk * 32 + 4));
        xf1[kk] = cvt8(ldg4(xp1 + kk * 32), ldg4(xp1 + kk * 32 + 4));
    }

    const float* wp = W1 + (size_t)(h0 + lm) * F2 + lk;
    f4 accA0 = {0.f,0.f,0.f,0.f}, accA1 = {0.f,0.f,0.f,0.f};
    f4 accC0 = {0.f,0.f,0.f,0.f}, accC1 = {0.f,0.f,0.f,0.f};
    #pragma unroll
    for (int kk = 0; kk < 4; ++kk) {
        h8 wa = cvt8(ldg4(wp + kk * 32), ldg4(wp + kk * 32 + 4));
        h8 wb = cvt8(ldg4(wp + F + kk * 32), ldg4(wp + F + kk * 32 + 4));
        // swapped: D[row=m][col-> 4 consecutive h per lane-quad]
        accA0 = __builtin_amdgcn_mfma_f32_16x16x32_f16(wa, xf0[kk], accA0, 0, 0, 0);
        accC0 = __builtin_amdgcn_mfma_f32_16x16x32_f16(wb, xf0[kk], accC0, 0, 0, 0);
        accA1 = __builtin_amdgcn_mfma_f32_16x16x32_f16(wa, xf1[kk], accA1, 0, 0, 0);
        accC1 = __builtin_amdgcn_mfma_f32_16x16x32_f16(wb, xf1[kk], accC1, 0, 0, 0);
    }

    const int hq = h0 + lq;                    // 4 consecutive h
    const float4 bq = ldg4(b1 + hq);
    #pragma unroll
    for (int mt = 0; mt < 2; ++mt) {
        const f4 aA = mt ? accA1 : accA0;
        const f4 aC = mt ? accC1 : accC0;
        const int m = m0 + mt * 16 + lm;       // global row (b*C + i)
        {
            h2 v01 = pkrtz(aA[0] + bq.x, aA[1] + bq.y);
            h2 v23 = pkrtz(aA[2] + bq.z, aA[3] + bq.w);
            h4 v; v[0] = v01[0]; v[1] = v01[1]; v[2] = v23[0]; v[3] = v23[1];
            *(h4*)(Ah + (size_t)m * H + hq) = v;           // one 8B store
        }
        {
            h2 v01 = pkrtz(aC[0], aC[1]);
            h2 v23 = pkrtz(aC[2], aC[3]);
            h4 v; v[0] = v01[0]; v[1] = v01[1]; v[2] = v23[0]; v[3] = v23[1];
            // CP8[((b*HOCT + hq>>3)*C + i)*8 + (hq&7)], hq&7 in {0,4}
            *(h4*)(CP8 + (((size_t)((m >> 8) * HOCT + (hq >> 3)) * C + (m & 255)) << 3)
                       + (hq & 7)) = v;                    // one 8B store
        }
    }

    if (blockIdx.x == 0 && t < 128) {   // w2 -> fp16 once
        float2 wv = ((const float2*)w2)[t];
        ((h2*)w2h)[t] = pkrtz(wv.x, wv.y);
    }
}

// ---------------- Kernel 2: pairwise relu-dot + sigmoid (R14 verbatim) -----
// Grid 512 = b(8) x it(32) x jh(2). Block 512 thr = 128 j x 4 h-splits.
// hs readfirstlane'd -> A-octet and w2 loads provably uniform -> SMEM pipe.
constexpr int TI = 8;
constexpr int HS = 4;
constexpr int JW = 128;   // j per block

__global__ __launch_bounds__(512) void k2_pair(
    const _Float16* __restrict__ Ah, const _Float16* __restrict__ CP8,
    const _Float16* __restrict__ w2h, const float* __restrict__ b2p,
    float* __restrict__ out)
{
    __shared__ float red[(HS - 1) * TI * JW];   // 12 KB
    const int t   = threadIdx.x;
    const int jl  = t & (JW - 1);
    const int hs  = __builtin_amdgcn_readfirstlane(t >> 7);  // wave-uniform, SGPR
    const int blk = blockIdx.x;
    const int jh  = blk & 1;
    const int it  = (blk >> 1) & 31;
    const int b   = blk >> 6;
    const int i0  = it * TI;
    const int j   = jh * JW + jl;

    float acc[TI];
    #pragma unroll
    for (int ii = 0; ii < TI; ++ii) acc[ii] = 0.f;

    const int g0 = hs * (HOCT / HS);           // 8 octets per split (SGPR)
    const _Float16* Ab = Ah + (size_t)(b * C + i0) * H;

    #pragma unroll 2
    for (int g = 0; g < HOCT / HS; ++g) {
        const int hb = g0 + g;                                // SGPR
        h8 cc = *(const h8*)(CP8 + (((size_t)(b * HOCT + hb) * C + j) << 3));
        HU uw; uw.v = *(const h8*)(w2h + hb * 8);             // uniform -> s_load
        #pragma unroll
        for (int ii = 0; ii < TI; ++ii) {
            h8 ao = *(const h8*)(Ab + ii * H + hb * 8);       // uniform -> s_load
            const h8 z = {0, 0, 0, 0, 0, 0, 0, 0};
            h8 s = __builtin_elementwise_max(ao + cc, z);     // pk_add + pk_max
            HU us; us.v = s;
            float a0 = acc[ii];
            a0 = fdot2(us.p[0], uw.p[0], a0);                 // v_dot2_f32_f16
            a0 = fdot2(us.p[1], uw.p[1], a0);
            a0 = fdot2(us.p[2], uw.p[2], a0);
            a0 = fdot2(us.p[3], uw.p[3], a0);
            acc[ii] = a0;
        }
    }

    if (hs > 0) {
        #pragma unroll
        for (int ii = 0; ii < TI; ++ii)
            red[((hs - 1) * TI + ii) * JW + jl] = acc[ii];
    }
    __syncthreads();
    if (hs == 0) {
        const float bb = b2p[0];
        #pragma unroll
        for (int ii = 0; ii < TI; ++ii) {
            float x = acc[ii]
                    + red[(0 * TI + ii) * JW + jl]
                    + red[(1 * TI + ii) * JW + jl]
                    + red[(2 * TI + ii) * JW + jl] + bb;
            out[(size_t)(b * C + i0 + ii) * C + j] = 1.f / (1.f + __expf(-x));
        }
    }
}

extern "C" void kernel_launch(void* const* d_in, const int* in_sizes, int n_in,
                              void* d_out, int out_size, void* d_ws, size_t ws_size,
                              hipStream_t stream) {
    const float* xa = (const float*)d_in[0];
    const float* W1 = (const float*)d_in[1];
    const float* b1 = (const float*)d_in[2];
    const float* w2 = (const float*)d_in[3];
    const float* b2 = (const float*)d_in[4];
    float* out = (float*)d_out;

    _Float16* Ah  = (_Float16*)d_ws;                  // 1 MB
    _Float16* CP8 = Ah  + (size_t)B * C * H;          // 1 MB
    _Float16* w2h = CP8 + (size_t)B * H * C;          // 512 B

    k1_mfma<<<256, 256, 0, stream>>>(xa, W1, b1, w2, Ah, CP8, w2h);
    k2_pair<<<512, 512, 0, stream>>>(Ah, CP8, w2h, b2, out);
}

// Round 17
// 20.245 us; speedup vs baseline: 2.7908x; 1.0601x over previous
//
#include <hip/hip_runtime.h>

// EdgeSelectionRL: out[b,i,j] = sigmoid( sum_h relu(A[b,i,h] + Cc[b,j,h]) * w2[h] + b2 )
// A = xa·Wa^T + b1, Cc = xa·Wb^T.  B=8, C=256, F=128, H=256.
// R17 = exact revert to R14 (session best, 20.49us): k1 = R4 MFMA projection
// (direct-form mfma(X,W), in-register f32->f16 cvt), k2 = readfirstlane-uniform
// fp16 dot2 pairwise. R16's swapped-k1 regressed (+1.0us) -> reverted.
// Ledger: fused 1-node dead (45-182us x5); occupancy/TI retunes worse;
// residual = ~16us submission floor + 2 nodes + ~4us device work (~floor).

typedef _Float16 h2 __attribute__((ext_vector_type(2)));
typedef _Float16 h8 __attribute__((ext_vector_type(8)));
typedef float    f4 __attribute__((ext_vector_type(4)));

constexpr int B  = 8;
constexpr int C  = 256;
constexpr int F  = 128;
constexpr int H  = 256;
constexpr int F2 = 2 * F;     // 256
constexpr int HOCT = H / 8;   // 32

#if __has_builtin(__builtin_amdgcn_fdot2)
__device__ __forceinline__ float fdot2(h2 a, h2 b, float c) {
    return __builtin_amdgcn_fdot2(a, b, c, false);
}
#else
__device__ __forceinline__ float fdot2(h2 a, h2 b, float c) {
    return c + (float)a.x * (float)b.x + (float)a.y * (float)b.y;
}
#endif

union HU { h8 v; h2 p[4]; };

__device__ __forceinline__ h2 pkrtz(float x, float y) {
    return __builtin_bit_cast(h2, __builtin_amdgcn_cvt_pkrtz(x, y));
}

__device__ __forceinline__ h8 cvt8(float4 a, float4 b) {
    HU u;
    u.p[0] = pkrtz(a.x, a.y);
    u.p[1] = pkrtz(a.z, a.w);
    u.p[2] = pkrtz(b.x, b.y);
    u.p[3] = pkrtz(b.z, b.w);
    return u.v;
}

// ---------------- Kernel 1: fused cvt + projections via MFMA (R4 verbatim) --
// Wave w: 2 m-tiles at (w>>4)*32, h-tile (w&15)*16. Direct f32 global fragment
// loads, cvt in-register. D layout (m89): lane l, reg r -> row m0+(l>>4)*4+r,
// col h0+(l&15).
__global__ __launch_bounds__(256) void k1_mfma(
    const float* __restrict__ xa, const float* __restrict__ W1,
    const float* __restrict__ b1, const float* __restrict__ w2,
    _Float16* __restrict__ Ah, _Float16* __restrict__ CP8,
    _Float16* __restrict__ w2h)
{
    const int t  = threadIdx.x;
    const int w  = blockIdx.x * 4 + (t >> 6);   // 0..1023
    const int l  = t & 63;
    const int mg = w >> 4;                      // 0..63
    const int h0 = (w & 15) * 16;
    const int lm = l & 15;
    const int lk = (l >> 4) * 8;
    const int m0 = mg * 32;

    h8 af[2][4];
    const float* xp0 = xa + (size_t)(m0 + lm) * F + lk;
    const float* xp1 = xp0 + 16 * F;
    #pragma unroll
    for (int kk = 0; kk < 4; ++kk) {
        af[0][kk] = cvt8(*(const float4*)(xp0 + kk * 32),
                         *(const float4*)(xp0 + kk * 32 + 4));
        af[1][kk] = cvt8(*(const float4*)(xp1 + kk * 32),
                         *(const float4*)(xp1 + kk * 32 + 4));
    }

    const float* wp = W1 + (size_t)(h0 + lm) * F2 + lk;
    f4 accA0 = {0.f,0.f,0.f,0.f}, accA1 = {0.f,0.f,0.f,0.f};
    f4 accC0 = {0.f,0.f,0.f,0.f}, accC1 = {0.f,0.f,0.f,0.f};
    #pragma unroll
    for (int kk = 0; kk < 4; ++kk) {
        h8 ba = cvt8(*(const float4*)(wp + kk * 32),
                     *(const float4*)(wp + kk * 32 + 4));
        h8 bb = cvt8(*(const float4*)(wp + F + kk * 32),
                     *(const float4*)(wp + F + kk * 32 + 4));
        accA0 = __builtin_amdgcn_mfma_f32_16x16x32_f16(af[0][kk], ba, accA0, 0, 0, 0);
        accC0 = __builtin_amdgcn_mfma_f32_16x16x32_f16(af[0][kk], bb, accC0, 0, 0, 0);
        accA1 = __builtin_amdgcn_mfma_f32_16x16x32_f16(af[1][kk], ba, accA1, 0, 0, 0);
        accC1 = __builtin_amdgcn_mfma_f32_16x16x32_f16(af[1][kk], bb, accC1, 0, 0, 0);
    }

    const int h  = h0 + lm;
    const float bh = b1[h];
    #pragma unroll
    for (int mt = 0; mt < 2; ++mt) {
        const f4 aA = mt ? accA1 : accA0;
        const f4 aC = mt ? accC1 : accC0;
        const int mb = m0 + mt * 16 + (l >> 4) * 4;
        #pragma unroll
        for (int r = 0; r < 4; ++r) {
            const int m = mb + r;
            Ah[(size_t)m * H + h] = (_Float16)(aA[r] + bh);
            // h-octet-packed Cc: CP8[((b*HOCT+h/8)*C + i)*8 + (h&7)]
            CP8[(((size_t)((m >> 8) * HOCT + (h >> 3)) * C + (m & 255)) << 3) + (h & 7)]
                = (_Float16)aC[r];
        }
    }

    if (blockIdx.x == 0 && t < 128) {   // w2 -> fp16 once
        float2 wv = ((const float2*)w2)[t];
        ((h2*)w2h)[t] = pkrtz(wv.x, wv.y);
    }
}

// ---------------- Kernel 2: pairwise relu-dot + sigmoid --------------------
// Grid 512 = b(8) x it(32) x jh(2). Block 512 thr = 128 j x 4 h-splits.
// hs is readfirstlane'd -> A-octet and w2 loads are PROVABLY uniform ->
// s_load_dwordx4 (SMEM pipe), freeing VMEM issue + address VALU.
// cc octets 16B/lane coalesced VMEM, slab j-half read once per block.
constexpr int TI = 8;
constexpr int HS = 4;
constexpr int JW = 128;   // j per block

__global__ __launch_bounds__(512) void k2_pair(
    const _Float16* __restrict__ Ah, const _Float16* __restrict__ CP8,
    const _Float16* __restrict__ w2h, const float* __restrict__ b2p,
    float* __restrict__ out)
{
    __shared__ float red[(HS - 1) * TI * JW];   // 12 KB
    const int t   = threadIdx.x;
    const int jl  = t & (JW - 1);
    const int hs  = __builtin_amdgcn_readfirstlane(t >> 7);  // wave-uniform, SGPR
    const int blk = blockIdx.x;
    const int jh  = blk & 1;
    const int it  = (blk >> 1) & 31;
    const int b   = blk >> 6;
    const int i0  = it * TI;
    const int j   = jh * JW + jl;

    float acc[TI];
    #pragma unroll
    for (int ii = 0; ii < TI; ++ii) acc[ii] = 0.f;

    const int g0 = hs * (HOCT / HS);           // 8 octets per split (SGPR)
    const _Float16* Ab = Ah + (size_t)(b * C + i0) * H;

    #pragma unroll 2
    for (int g = 0; g < HOCT / HS; ++g) {
        const int hb = g0 + g;                                // SGPR
        h8 cc = *(const h8*)(CP8 + (((size_t)(b * HOCT + hb) * C + j) << 3));
        HU uw; uw.v = *(const h8*)(w2h + hb * 8);             // uniform -> s_load
        #pragma unroll
        for (int ii = 0; ii < TI; ++ii) {
            h8 ao = *(const h8*)(Ab + ii * H + hb * 8);       // uniform -> s_load
            const h8 z = {0, 0, 0, 0, 0, 0, 0, 0};
            h8 s = __builtin_elementwise_max(ao + cc, z);     // pk_add + pk_max
            HU us; us.v = s;
            float a0 = acc[ii];
            a0 = fdot2(us.p[0], uw.p[0], a0);                 // v_dot2_f32_f16
            a0 = fdot2(us.p[1], uw.p[1], a0);
            a0 = fdot2(us.p[2], uw.p[2], a0);
            a0 = fdot2(us.p[3], uw.p[3], a0);
            acc[ii] = a0;
        }
    }

    if (hs > 0) {
        #pragma unroll
        for (int ii = 0; ii < TI; ++ii)
            red[((hs - 1) * TI + ii) * JW + jl] = acc[ii];
    }
    __syncthreads();
    if (hs == 0) {
        const float bb = b2p[0];
        #pragma unroll
        for (int ii = 0; ii < TI; ++ii) {
            float x = acc[ii]
                    + red[(0 * TI + ii) * JW + jl]
                    + red[(1 * TI + ii) * JW + jl]
                    + red[(2 * TI + ii) * JW + jl] + bb;
            out[(size_t)(b * C + i0 + ii) * C + j] = 1.f / (1.f + __expf(-x));
        }
    }
}

extern "C" void kernel_launch(void* const* d_in, const int* in_sizes, int n_in,
                              void* d_out, int out_size, void* d_ws, size_t ws_size,
                              hipStream_t stream) {
    const float* xa = (const float*)d_in[0];
    const float* W1 = (const float*)d_in[1];
    const float* b1 = (const float*)d_in[2];
    const float* w2 = (const float*)d_in[3];
    const float* b2 = (const float*)d_in[4];
    float* out = (float*)d_out;

    _Float16* Ah  = (_Float16*)d_ws;                  // 1 MB
    _Float16* CP8 = Ah  + (size_t)B * C * H;          // 1 MB
    _Float16* w2h = CP8 + (size_t)B * H * C;          // 512 B

    k1_mfma<<<256, 256, 0, stream>>>(xa, W1, b1, w2, Ah, CP8, w2h);
    k2_pair<<<512, 512, 0, stream>>>(Ah, CP8, w2h, b2, out);
}